// Round 16
// baseline (44.431 us; speedup 1.0000x reference)
//
#include <hip/hip_runtime.h>

typedef __attribute__((ext_vector_type(4))) float f32x4;
typedef unsigned int u32;
typedef long i64;

#define NROWS 8192
#define HALF  4096
#define DIM   256
#define TEMP_INV 2.0f                 // 1/temperature
#define NBT 64                        // 8192/128 tiles per side
#define NBLK (NBT * (NBT + 1) / 2)    // 2080 triangular tiles
#define NSLAB 128                     // 64 row-slots + 64 col-slots

#define BARRIER() asm volatile("s_barrier" ::: "memory")
#define WAITV(n)  asm volatile("s_waitcnt vmcnt(" #n ")" ::: "memory")

// ------- kernel 1: normalize rows -> fp8 e4m3, and zero the slab ------------
__global__ __launch_bounds__(256) void normalize_k(const float* __restrict__ zi,
                                                   const float* __restrict__ zj,
                                                   u32* __restrict__ zn8,
                                                   float4* __restrict__ slab4) {
    const int row  = blockIdx.x * 4 + (threadIdx.x >> 6);
    const int lane = threadIdx.x & 63;
    const float* src = (row < HALF) ? (zi + (size_t)row * DIM)
                                    : (zj + (size_t)(row - HALF) * DIM);
    float4 v = reinterpret_cast<const float4*>(src)[lane];
    float ss = v.x * v.x + v.y * v.y + v.z * v.z + v.w * v.w;
    #pragma unroll
    for (int m = 32; m; m >>= 1) ss += __shfl_xor(ss, m);
    const float inv = 1.0f / fmaxf(sqrtf(ss), 1e-8f);
    u32 pk = __builtin_amdgcn_cvt_pk_fp8_f32(v.x * inv, v.y * inv, 0, false);
    pk     = __builtin_amdgcn_cvt_pk_fp8_f32(v.z * inv, v.w * inv, pk, true);
    zn8[(size_t)row * (DIM / 4) + lane] = pk;
    const int gt = blockIdx.x * 256 + threadIdx.x;
    if (gt < (NSLAB * NROWS) / 4)
        slab4[gt] = float4{0.f, 0.f, 0.f, 0.f};
}

// ------- kernel 2: single-barrier fp8 triangular GEMM, ping-pong ni-loop ----
// A (32x256 fp8) in 32 VGPR/lane; full B-tile (128x256 = 32 KB) staged once;
// one vmcnt(0)+barrier; then a rolled x2 ni-loop with named ping-pong B-frag
// buffers: prefetch ni+1's 8 ds_read_b64 while ni's 16 MFMA + fold run.
__device__ __forceinline__ void gload16(const void* g, void* lds) {
    __builtin_amdgcn_global_load_lds(
        (const __attribute__((address_space(1))) u32*)g,
        (__attribute__((address_space(3))) u32*)lds, 16, 0, 0);
}

__global__ __launch_bounds__(256, 4) void gemm_exp_rowsum(
        const unsigned char* __restrict__ zn8,
        float* __restrict__ slab, float* __restrict__ pos) {
    // XCD-aware bijective swizzle (2080 = 8 * 260)
    const int b0 = blockIdx.x;
    const int b  = (b0 & 7) * (NBLK / 8) + (b0 >> 3);
    // Triangular decode: b -> (by, bx), by <= bx < 64
    int by = (int)((129.0f - sqrtf(129.0f * 129.0f - 8.0f * (float)b)) * 0.5f);
    while (by * (129 - by) / 2 > b) --by;
    while ((by + 1) * (129 - (by + 1)) / 2 <= b) ++by;
    const int bx = by + (b - by * (129 - by) / 2);
    const bool diag  = (by == bx);
    const bool isPos = (bx - by == 32);

    const int rowBase = by * 128;
    const int colBase = bx * 128;

    __shared__ char LDSB[32768];    // full B-tile; reused for col-reduce

    const int tid  = threadIdx.x;
    const int w    = tid >> 6;      // 0..3, wave owns rows [w*32, +32)
    const int lane = tid & 63;

    // ---- A -> registers: frag(mi,ks) = 8 fp8 of row w*32+mi*16+(lane&15),
    // k in [ks*32 + (lane>>4)*8, +8)
    i64 ar[2][8];
    const unsigned char* aBase = zn8
        + (size_t)(rowBase + w * 32 + (lane & 15)) * DIM + (lane >> 4) * 8;
    #pragma unroll
    for (int mi = 0; mi < 2; ++mi)
        #pragma unroll
        for (int ks = 0; ks < 8; ++ks)
            ar[mi][ks] = *reinterpret_cast<const i64*>(
                aBase + (size_t)mi * 16 * DIM + ks * 32);

    // ---- stage full B-tile: LDS row r at r*256; 16B unit u holds global
    // unit u ^ (r&7) (both-sides swizzle; spreads 8 bank-groups on read).
    #pragma unroll
    for (int j = 0; j < 8; ++j) {
        const int r  = (j * 4 + w) * 4 + (lane >> 4);
        const int gq = (lane & 15) ^ (r & 7);
        gload16(zn8 + (size_t)(colBase + r) * DIM + gq * 16,
                LDSB + (j * 4 + w) * 1024);
    }
    WAITV(0);      // A regs + all LDS writes landed
    BARRIER();     // whole B-tile visible; no further inter-wave sync

    const int rowByte = (lane & 15) * 256 + ((lane >> 4) & 1) * 8;
    const int k8      = lane & 7;
    const int hq      = (lane >> 4) >> 1;

    float rs[2][4] = {};
    float csv[8];
    float posv[2]  = {0.f, 0.f};

    auto rdNi = [&](i64* buf, int ni) {
        #pragma unroll
        for (int ks = 0; ks < 8; ++ks) {
            const int off = ni * 4096 + rowByte + (((ks * 2 + hq) ^ k8) << 4);
            buf[ks] = *reinterpret_cast<const i64*>(LDSB + off);
        }
    };
    auto doNi = [&](const i64* buf, int ni) {
        f32x4 a0 = {0.f, 0.f, 0.f, 0.f}, a1 = {0.f, 0.f, 0.f, 0.f};
        #pragma unroll
        for (int ks = 0; ks < 8; ++ks) {
            a0 = __builtin_amdgcn_mfma_f32_16x16x32_fp8_fp8(ar[0][ks], buf[ks], a0, 0, 0, 0);
            a1 = __builtin_amdgcn_mfma_f32_16x16x32_fp8_fp8(ar[1][ks], buf[ks], a1, 0, 0, 0);
        }
        float cacc = 0.f;
        #pragma unroll
        for (int v = 0; v < 4; ++v) {
            const int C  = ni * 16 + (lane & 15);
            const int R0 = w * 32 + (lane >> 4) * 4 + v;
            const int R1 = R0 + 16;
            float e0 = __expf(TEMP_INV * a0[v]);
            float e1 = __expf(TEMP_INV * a1[v]);
            if (isPos && R0 == C) posv[0] = a0[v];
            if (isPos && R1 == C) posv[1] = a1[v];
            if (diag && R0 == C) e0 = 0.f;
            if (diag && R1 == C) e1 = 0.f;
            rs[0][v] += e0; rs[1][v] += e1;
            cacc += e0 + e1;
        }
        csv[ni] = cacc;
    };

    // ping-pong pipelined ni-loop: prefetch ni+1 while computing ni
    i64 bA[8], bB[8];
    rdNi(bA, 0);
    #pragma clang loop unroll(disable)
    for (int nn = 0; nn < 4; ++nn) {
        const int e = nn * 2, o = e + 1;
        rdNi(bB, o);               // prefetch odd while even computes
        doNi(bA, e);
        if (nn < 3) rdNi(bA, o + 1);  // prefetch next even while odd computes
        doNi(bB, o);
    }

    // ---- row sums: allreduce across the 16 col-lanes, coalesced store
    float* rowSlot = slab + (size_t)bx * NROWS + rowBase + w * 32;
    #pragma unroll
    for (int mi = 0; mi < 2; ++mi) {
        f32x4 r;
        #pragma unroll
        for (int v = 0; v < 4; ++v) {
            float s = rs[mi][v];
            s += __shfl_xor(s, 1);
            s += __shfl_xor(s, 2);
            s += __shfl_xor(s, 4);
            s += __shfl_xor(s, 8);
            r[v] = s;
        }
        if ((lane & 15) == 0)
            *reinterpret_cast<f32x4*>(rowSlot + mi * 16 + (lane >> 4) * 4) = r;
    }

    // ---- col sums: per-wave reduce, cross-wave via reused LDS
    __syncthreads();                    // all B reads done; LDSB reusable
    float* colred = reinterpret_cast<float*>(LDSB);
    #pragma unroll
    for (int g = 0; g < 8; ++g) {       // col = g*16 + (lane&15)
        float c = csv[g];
        c += __shfl_xor(c, 16);
        c += __shfl_xor(c, 32);
        if (lane < 16) colred[w * 128 + g * 16 + lane] = c;
    }
    __syncthreads();
    if (tid < 128) {
        const float sum = colred[tid] + colred[128 + tid]
                        + colred[256 + tid] + colred[384 + tid];
        // diag tile fully covered by row sums -> keep slot zero-consistent
        slab[(size_t)(64 + by) * NROWS + colBase + tid] = diag ? 0.f : sum;
    }

    // ---- positives: tile diagonal of isPos blocks (pre-exp values)
    if (isPos) {
        const int vq = (lane & 15) - (lane >> 4) * 4;
        if (vq >= 0 && vq < 4) {
            #pragma unroll
            for (int mi = 0; mi < 2; ++mi) {
                const int Rg = rowBase + w * 32 + mi * 16 + (lane & 15);
                pos[Rg] = posv[mi];
                pos[Rg + HALF] = posv[mi];
            }
        }
    }
}

// ------- kernel 3: reduce all 128 slab slots (zero-inited) ------------------
__global__ __launch_bounds__(256) void finalize_k(const float* __restrict__ slab,
                                                  const float* __restrict__ pos,
                                                  float* __restrict__ part) {
    const int row = blockIdx.x * 256 + threadIdx.x;
    float d = 0.f;
    #pragma unroll 8
    for (int j = 0; j < NSLAB; ++j)
        d += slab[(size_t)j * NROWS + row];    // coalesced across threads
    float s = logf(d) - TEMP_INV * pos[row];
    __shared__ float red[256];
    red[threadIdx.x] = s;
    __syncthreads();
    #pragma unroll
    for (int m = 128; m; m >>= 1) {
        if (threadIdx.x < m) red[threadIdx.x] += red[threadIdx.x + m];
        __syncthreads();
    }
    if (threadIdx.x == 0) part[blockIdx.x] = red[0];
}

// ------- kernel 4: sum 32 partials (deterministic, no atomics) --------------
__global__ __launch_bounds__(64) void sum_k(const float* __restrict__ part,
                                            float* __restrict__ out) {
    float v = (threadIdx.x < 32) ? part[threadIdx.x] : 0.f;
    #pragma unroll
    for (int m = 32; m; m >>= 1) v += __shfl_xor(v, m);
    if (threadIdx.x == 0) out[0] = v * (1.0f / NROWS);
}

extern "C" void kernel_launch(void* const* d_in, const int* in_sizes, int n_in,
                              void* d_out, int out_size, void* d_ws, size_t ws_size,
                              hipStream_t stream) {
    const float* zi = (const float*)d_in[0];
    const float* zj = (const float*)d_in[1];
    float* out = (float*)d_out;

    // workspace: zn8 fp8 [8192][256] (2 MiB) | slab f32 [128][8192] (4 MiB)
    //            | pos f32 [8192] | part f32 [32]
    unsigned char* zn8 = (unsigned char*)d_ws;
    float* slab = (float*)((char*)d_ws + (size_t)NROWS * DIM);
    float* pos  = slab + (size_t)NSLAB * NROWS;
    float* part = pos + NROWS;

    normalize_k<<<NROWS / 4, 256, 0, stream>>>(zi, zj, (u32*)zn8, (float4*)slab);
    gemm_exp_rowsum<<<NBLK, 256, 0, stream>>>(zn8, slab, pos);
    finalize_k<<<NROWS / 256, 256, 0, stream>>>(slab, pos, part);
    sum_k<<<1, 64, 0, stream>>>(part, out);
}

// Round 17
// 43.056 us; speedup vs baseline: 1.0319x; 1.0319x over previous
//
#include <hip/hip_runtime.h>

typedef __attribute__((ext_vector_type(4))) float f32x4;
typedef unsigned int u32;
typedef long i64;

#define NROWS 8192
#define HALF  4096
#define DIM   256
#define TEMP_INV 2.0f                 // 1/temperature
#define NBT 64                        // 8192/128 tiles per side
#define NBLK (NBT * (NBT + 1) / 2)    // 2080 triangular tiles
#define NSLAB 128                     // 64 row-slots + 64 col-slots
#define NFIN  128                     // finalize blocks (64 rows each)

#define BARRIER() asm volatile("s_barrier" ::: "memory")
#define WAITV(n)  asm volatile("s_waitcnt vmcnt(" #n ")" ::: "memory")

// ------- kernel 1: normalize rows -> fp8 e4m3, zero slab + ticket -----------
__global__ __launch_bounds__(256) void normalize_k(const float* __restrict__ zi,
                                                   const float* __restrict__ zj,
                                                   u32* __restrict__ zn8,
                                                   float4* __restrict__ slab4,
                                                   u32* __restrict__ ticket) {
    const int row  = blockIdx.x * 4 + (threadIdx.x >> 6);
    const int lane = threadIdx.x & 63;
    const float* src = (row < HALF) ? (zi + (size_t)row * DIM)
                                    : (zj + (size_t)(row - HALF) * DIM);
    float4 v = reinterpret_cast<const float4*>(src)[lane];
    float ss = v.x * v.x + v.y * v.y + v.z * v.z + v.w * v.w;
    #pragma unroll
    for (int m = 32; m; m >>= 1) ss += __shfl_xor(ss, m);
    const float inv = 1.0f / fmaxf(sqrtf(ss), 1e-8f);
    u32 pk = __builtin_amdgcn_cvt_pk_fp8_f32(v.x * inv, v.y * inv, 0, false);
    pk     = __builtin_amdgcn_cvt_pk_fp8_f32(v.z * inv, v.w * inv, pk, true);
    zn8[(size_t)row * (DIM / 4) + lane] = pk;
    const int gt = blockIdx.x * 256 + threadIdx.x;
    if (gt < (NSLAB * NROWS) / 4)
        slab4[gt] = float4{0.f, 0.f, 0.f, 0.f};
    if (gt == 0) *ticket = 0;
}

// ------- kernel 2: single-barrier fp8 triangular GEMM, ping-pong ni-loop ----
// Stage B FIRST, then A-loads (order pinned); WAITV(16) releases the barrier
// as soon as the 8 gload16s retire -- A-load latency is absorbed by the
// compiler's own vmcnt before the first MFMA, overlapped with rdNi(0).
__device__ __forceinline__ void gload16(const void* g, void* lds) {
    __builtin_amdgcn_global_load_lds(
        (const __attribute__((address_space(1))) u32*)g,
        (__attribute__((address_space(3))) u32*)lds, 16, 0, 0);
}

__global__ __launch_bounds__(256, 4) void gemm_exp_rowsum(
        const unsigned char* __restrict__ zn8,
        float* __restrict__ slab, float* __restrict__ pos) {
    // XCD-aware bijective swizzle (2080 = 8 * 260)
    const int b0 = blockIdx.x;
    const int b  = (b0 & 7) * (NBLK / 8) + (b0 >> 3);
    // Triangular decode: b -> (by, bx), by <= bx < 64
    int by = (int)((129.0f - sqrtf(129.0f * 129.0f - 8.0f * (float)b)) * 0.5f);
    while (by * (129 - by) / 2 > b) --by;
    while ((by + 1) * (129 - (by + 1)) / 2 <= b) ++by;
    const int bx = by + (b - by * (129 - by) / 2);
    const bool diag  = (by == bx);
    const bool isPos = (bx - by == 32);

    const int rowBase = by * 128;
    const int colBase = bx * 128;

    __shared__ char LDSB[32768];    // full B-tile; reused for col-reduce

    const int tid  = threadIdx.x;
    const int w    = tid >> 6;      // 0..3, wave owns rows [w*32, +32)
    const int lane = tid & 63;

    // ---- stage full B-tile FIRST: LDS row r at r*256; 16B unit u holds
    // global unit u ^ (r&7) (both-sides swizzle).
    #pragma unroll
    for (int j = 0; j < 8; ++j) {
        const int r  = (j * 4 + w) * 4 + (lane >> 4);
        const int gq = (lane & 15) ^ (r & 7);
        gload16(zn8 + (size_t)(colBase + r) * DIM + gq * 16,
                LDSB + (j * 4 + w) * 1024);
    }
    asm volatile("" ::: "memory");   // pin: A-loads must issue AFTER the stages

    // ---- A -> registers: frag(mi,ks) = 8 fp8 of row w*32+mi*16+(lane&15)
    i64 ar[2][8];
    const unsigned char* aBase = zn8
        + (size_t)(rowBase + w * 32 + (lane & 15)) * DIM + (lane >> 4) * 8;
    #pragma unroll
    for (int mi = 0; mi < 2; ++mi)
        #pragma unroll
        for (int ks = 0; ks < 8; ++ks)
            ar[mi][ks] = *reinterpret_cast<const i64*>(
                aBase + (size_t)mi * 16 * DIM + ks * 32);

    WAITV(16);     // 8 oldest (the stages) retired; 16 A-loads still in flight
    BARRIER();     // whole B-tile visible; no further inter-wave sync

    const int rowByte = (lane & 15) * 256 + ((lane >> 4) & 1) * 8;
    const int k8      = lane & 7;
    const int hq      = (lane >> 4) >> 1;

    float rs[2][4] = {};
    float csv[8];
    float posv[2]  = {0.f, 0.f};

    auto rdNi = [&](i64* buf, int ni) {
        #pragma unroll
        for (int ks = 0; ks < 8; ++ks) {
            const int off = ni * 4096 + rowByte + (((ks * 2 + hq) ^ k8) << 4);
            buf[ks] = *reinterpret_cast<const i64*>(LDSB + off);
        }
    };
    auto doNi = [&](const i64* buf, int ni) {
        f32x4 a0 = {0.f, 0.f, 0.f, 0.f}, a1 = {0.f, 0.f, 0.f, 0.f};
        #pragma unroll
        for (int ks = 0; ks < 8; ++ks) {
            a0 = __builtin_amdgcn_mfma_f32_16x16x32_fp8_fp8(ar[0][ks], buf[ks], a0, 0, 0, 0);
            a1 = __builtin_amdgcn_mfma_f32_16x16x32_fp8_fp8(ar[1][ks], buf[ks], a1, 0, 0, 0);
        }
        float cacc = 0.f;
        #pragma unroll
        for (int v = 0; v < 4; ++v) {
            const int C  = ni * 16 + (lane & 15);
            const int R0 = w * 32 + (lane >> 4) * 4 + v;
            const int R1 = R0 + 16;
            float e0 = __expf(TEMP_INV * a0[v]);
            float e1 = __expf(TEMP_INV * a1[v]);
            if (isPos && R0 == C) posv[0] = a0[v];
            if (isPos && R1 == C) posv[1] = a1[v];
            if (diag && R0 == C) e0 = 0.f;
            if (diag && R1 == C) e1 = 0.f;
            rs[0][v] += e0; rs[1][v] += e1;
            cacc += e0 + e1;
        }
        csv[ni] = cacc;
    };

    // ping-pong pipelined ni-loop: prefetch ni+1 while computing ni
    i64 bA[8], bB[8];
    rdNi(bA, 0);
    #pragma clang loop unroll(disable)
    for (int nn = 0; nn < 4; ++nn) {
        const int e = nn * 2, o = e + 1;
        rdNi(bB, o);
        doNi(bA, e);
        if (nn < 3) rdNi(bA, o + 1);
        doNi(bB, o);
    }

    // ---- row sums: allreduce across the 16 col-lanes, coalesced store
    float* rowSlot = slab + (size_t)bx * NROWS + rowBase + w * 32;
    #pragma unroll
    for (int mi = 0; mi < 2; ++mi) {
        f32x4 r;
        #pragma unroll
        for (int v = 0; v < 4; ++v) {
            float s = rs[mi][v];
            s += __shfl_xor(s, 1);
            s += __shfl_xor(s, 2);
            s += __shfl_xor(s, 4);
            s += __shfl_xor(s, 8);
            r[v] = s;
        }
        if ((lane & 15) == 0)
            *reinterpret_cast<f32x4*>(rowSlot + mi * 16 + (lane >> 4) * 4) = r;
    }

    // ---- col sums: per-wave reduce, cross-wave via reused LDS
    __syncthreads();                    // all B reads done; LDSB reusable
    float* colred = reinterpret_cast<float*>(LDSB);
    #pragma unroll
    for (int g = 0; g < 8; ++g) {       // col = g*16 + (lane&15)
        float c = csv[g];
        c += __shfl_xor(c, 16);
        c += __shfl_xor(c, 32);
        if (lane < 16) colred[w * 128 + g * 16 + lane] = c;
    }
    __syncthreads();
    if (tid < 128) {
        const float sum = colred[tid] + colred[128 + tid]
                        + colred[256 + tid] + colred[384 + tid];
        slab[(size_t)(64 + by) * NROWS + colBase + tid] = diag ? 0.f : sum;
    }

    // ---- positives: tile diagonal of isPos blocks (pre-exp values)
    if (isPos) {
        const int vq = (lane & 15) - (lane >> 4) * 4;
        if (vq >= 0 && vq < 4) {
            #pragma unroll
            for (int mi = 0; mi < 2; ++mi) {
                const int Rg = rowBase + w * 32 + mi * 16 + (lane & 15);
                pos[Rg] = posv[mi];
                pos[Rg + HALF] = posv[mi];
            }
        }
    }
}

// ------- kernel 3: slab reduce + loss, fused last-block final sum -----------
// 128 blocks x 64 rows; threads = 64 rows x 4 slot-groups (4x in-flight loads
// vs the old 32-block version). Last block (ticket) sums the 128 partials
// with device-coherent atomic reads -- deterministic (fixed order).
__global__ __launch_bounds__(256) void finalize_k(const float* __restrict__ slab,
                                                  const float* __restrict__ pos,
                                                  float* __restrict__ part,
                                                  u32* __restrict__ ticket,
                                                  float* __restrict__ out) {
    const int r   = threadIdx.x & 63;
    const int g   = threadIdx.x >> 6;
    const int row = blockIdx.x * 64 + r;
    float d = 0.f;
    #pragma unroll 8
    for (int j = g * 32; j < g * 32 + 32; ++j)
        d += slab[(size_t)j * NROWS + row];    // coalesced across r
    __shared__ float xch[4][64];
    xch[g][r] = d;
    __syncthreads();
    float s = 0.f;
    if (threadIdx.x < 64) {
        const float dd = xch[0][threadIdx.x] + xch[1][threadIdx.x]
                       + xch[2][threadIdx.x] + xch[3][threadIdx.x];
        s = logf(dd) - TEMP_INV * pos[blockIdx.x * 64 + threadIdx.x];
        #pragma unroll
        for (int m = 32; m; m >>= 1) s += __shfl_xor(s, m);
    }
    __shared__ u32 isLast;
    if (threadIdx.x == 0) {
        part[blockIdx.x] = s;
        __threadfence();                        // publish before counting
        isLast = (atomicAdd(ticket, 1u) == NFIN - 1) ? 1u : 0u;
    }
    __syncthreads();
    if (isLast && threadIdx.x < 64) {
        // coherent reads of all 128 partials (atomic fetch-add 0)
        float v = atomicAdd(&part[threadIdx.x], 0.0f)
                + atomicAdd(&part[threadIdx.x + 64], 0.0f);
        #pragma unroll
        for (int m = 32; m; m >>= 1) v += __shfl_xor(v, m);
        if (threadIdx.x == 0) out[0] = v * (1.0f / NROWS);
    }
}

extern "C" void kernel_launch(void* const* d_in, const int* in_sizes, int n_in,
                              void* d_out, int out_size, void* d_ws, size_t ws_size,
                              hipStream_t stream) {
    const float* zi = (const float*)d_in[0];
    const float* zj = (const float*)d_in[1];
    float* out = (float*)d_out;

    // workspace: zn8 fp8 [8192][256] (2 MiB) | slab f32 [128][8192] (4 MiB)
    //            | pos f32 [8192] | part f32 [128] | ticket u32
    unsigned char* zn8 = (unsigned char*)d_ws;
    float* slab = (float*)((char*)d_ws + (size_t)NROWS * DIM);
    float* pos  = slab + (size_t)NSLAB * NROWS;
    float* part = pos + NROWS;
    u32* ticket = (u32*)(part + NFIN);

    normalize_k<<<NROWS / 4, 256, 0, stream>>>(zi, zj, (u32*)zn8, (float4*)slab, ticket);
    gemm_exp_rowsum<<<NBLK, 256, 0, stream>>>(zn8, slab, pos);
    finalize_k<<<NFIN, 256, 0, stream>>>(slab, pos, part, ticket, out);
}